// Round 2
// baseline (462.565 us; speedup 1.0000x reference)
//
#include <hip/hip_runtime.h>
#include <hip/hip_bf16.h>
#include <math.h>

typedef __attribute__((ext_vector_type(4))) float f32x4;
typedef __attribute__((ext_vector_type(8))) short s16x8;
typedef __attribute__((ext_vector_type(4))) short s16x4;

#define S_LEN 4096
#define DMODEL 1024
#define NHEADS 16
#define DHEAD 64

__device__ __forceinline__ unsigned short f2bf(float f) {
  union { float f; unsigned int u; } x; x.f = f;
  return (unsigned short)((x.u + 0x7FFFu + ((x.u >> 16) & 1u)) >> 16);
}

// ---------------------------------------------------------------------------
// GEMM body: Y[m,n] = sum_k A[m,k] * W[n,k] + bias[n]
// M=4096, N=1024, K=1024.  Tile 128x128, BK=32, 4 waves, each wave 64x64.
// A_BF16: A is bf16 (ushort) else fp32 (cast to bf16 during staging).
// OUT_HEAD==1: bf16 out at [((n>>6)*4096 + m)*64 + (n&63)]  (head layout)
// OUT_HEAD==0: fp32 out at [m*1024 + n]
// ---------------------------------------------------------------------------
template<int A_BF16, int OUT_HEAD>
__device__ __forceinline__ void gemm_body(const void* __restrict__ Ap,
                                          const float* __restrict__ W,
                                          const float* __restrict__ bias,
                                          void* __restrict__ outp) {
  constexpr int K = DMODEL, N = DMODEL, M = S_LEN;
  constexpr int BM = 128, BK = 32, LDT = 40;  // pad 32->40: 2-way bank alias only
  __shared__ unsigned short Alds[BM * LDT];
  __shared__ unsigned short Blds[BM * LDT];
  const int tid = threadIdx.x;
  const int l = tid & 63, wid = tid >> 6;
  const int lr = l & 15, lg = l >> 4;
  const int bm = blockIdx.x * BM;
  const int bn = blockIdx.y * BM;
  const int wm = (wid >> 1) * 64, wn = (wid & 1) * 64;

  f32x4 acc[4][4] = {};

  for (int k0 = 0; k0 < K; k0 += BK) {
    __syncthreads();
    // ---- stage A tile (128 x 32) ----
    if constexpr (A_BF16) {
      const unsigned short* A = (const unsigned short*)Ap;
      const int col = (tid & 3) * 8, row = tid >> 2;
#pragma unroll
      for (int p = 0; p < 2; ++p) {
        const int r = row + p * 64;
        s16x8 vv = *(const s16x8*)(A + (size_t)(bm + r) * K + k0 + col);
        *(s16x8*)&Alds[r * LDT + col] = vv;
      }
    } else {
      const float* A = (const float*)Ap;
      const int col = (tid & 7) * 4, row = tid >> 3;
#pragma unroll
      for (int p = 0; p < 4; ++p) {
        const int r = row + p * 32;
        f32x4 vv = *(const f32x4*)(A + (size_t)(bm + r) * K + k0 + col);
        s16x4 o;
#pragma unroll
        for (int j = 0; j < 4; ++j) o[j] = (short)f2bf(vv[j]);
        *(s16x4*)&Alds[r * LDT + col] = o;
      }
    }
    // ---- stage B tile (128 x 32), always fp32 weights ----
    {
      const int col = (tid & 7) * 4, row = tid >> 3;
#pragma unroll
      for (int p = 0; p < 4; ++p) {
        const int r = row + p * 32;
        f32x4 vv = *(const f32x4*)(W + (size_t)(bn + r) * K + k0 + col);
        s16x4 o;
#pragma unroll
        for (int j = 0; j < 4; ++j) o[j] = (short)f2bf(vv[j]);
        *(s16x4*)&Blds[r * LDT + col] = o;
      }
    }
    __syncthreads();
    // ---- fragments + MFMA (16 per K-tile per wave) ----
    s16x8 af[4], bfr[4];
#pragma unroll
    for (int mi = 0; mi < 4; ++mi)
      af[mi] = *(const s16x8*)&Alds[(wm + mi * 16 + lr) * LDT + lg * 8];
#pragma unroll
    for (int ni = 0; ni < 4; ++ni)
      bfr[ni] = *(const s16x8*)&Blds[(wn + ni * 16 + lr) * LDT + lg * 8];
#pragma unroll
    for (int mi = 0; mi < 4; ++mi)
#pragma unroll
      for (int ni = 0; ni < 4; ++ni)
        acc[mi][ni] = __builtin_amdgcn_mfma_f32_16x16x32_bf16(af[mi], bfr[ni], acc[mi][ni], 0, 0, 0);
  }

  // ---- epilogue ----
#pragma unroll
  for (int ni = 0; ni < 4; ++ni) {
    const int n = bn + wn + ni * 16 + lr;
    const float bv = bias[n];
#pragma unroll
    for (int mi = 0; mi < 4; ++mi) {
#pragma unroll
      for (int j = 0; j < 4; ++j) {
        const int m = bm + wm + mi * 16 + lg * 4 + j;
        const float val = acc[mi][ni][j] + bv;
        if constexpr (OUT_HEAD) {
          unsigned short* out = (unsigned short*)outp;
          out[((size_t)(n >> 6) * M + m) * DHEAD + (n & 63)] = f2bf(val);
        } else {
          float* out = (float*)outp;
          out[(size_t)m * N + n] = val;
        }
      }
    }
  }
}

// q/k/v projections in one launch: blockIdx.z selects which.
__global__ __launch_bounds__(256) void proj3_kernel(
    const float* __restrict__ q, const float* __restrict__ k, const float* __restrict__ v,
    const float* __restrict__ wq, const float* __restrict__ bq,
    const float* __restrict__ wk, const float* __restrict__ bk,
    const float* __restrict__ wv, const float* __restrict__ bv,
    unsigned short* __restrict__ ws) {
  const int z = blockIdx.z;
  const float* A = (z == 0) ? q : (z == 1) ? k : v;
  const float* W = (z == 0) ? wq : (z == 1) ? wk : wv;
  const float* B = (z == 0) ? bq : (z == 1) ? bk : bv;
  unsigned short* out = ws + (size_t)z * S_LEN * DMODEL;
  gemm_body<0, 1>(A, W, B, out);
}

__global__ __launch_bounds__(256) void outproj_kernel(
    const unsigned short* __restrict__ concat, const float* __restrict__ wo,
    const float* __restrict__ bo, float* __restrict__ out) {
  gemm_body<1, 0>(concat, wo, bo, out);
}

// ---------------------------------------------------------------------------
// Flash attention: one block = one head x 64 q-rows (4 waves x 16 rows).
// KV blocks of 64 keys. fp32 online softmax, bf16 MFMA throughout.
// mask is int32 (harness passes integer/bool inputs as int*).
// ---------------------------------------------------------------------------
__global__ __launch_bounds__(256) void attn_fwd(
    const unsigned short* __restrict__ Qh, const unsigned short* __restrict__ Kh,
    const unsigned short* __restrict__ Vh, const int* __restrict__ mask,
    unsigned short* __restrict__ concat) {
  __shared__ unsigned short V_lds[64][72];      // [d][key], pad 8
  __shared__ unsigned short P_lds[4][16][72];   // per-wave P, pad 8
  const int tid = threadIdx.x;
  const int l = tid & 63, wid = tid >> 6;
  const int lr = l & 15, lg = l >> 4;
  const int h = blockIdx.y;
  const int qrow0 = blockIdx.x * 64 + wid * 16;

  // Q fragments held in registers for the whole kernel
  const unsigned short* Qbase = Qh + ((size_t)h * S_LEN + qrow0) * DHEAD;
  s16x8 qf[2];
#pragma unroll
  for (int ds = 0; ds < 2; ++ds)
    qf[ds] = *(const s16x8*)(Qbase + lr * DHEAD + ds * 32 + lg * 8);

  const unsigned short* Kbase = Kh + (size_t)h * S_LEN * DHEAD;
  const unsigned short* Vbase = Vh + (size_t)h * S_LEN * DHEAD;

  float m_run[4], l_run[4];
  f32x4 o_acc[4] = {};
#pragma unroll
  for (int j = 0; j < 4; ++j) { m_run[j] = -INFINITY; l_run[j] = 0.f; }

  const int vkey = tid >> 2, vdg = (tid & 3) * 16;

  for (int kb = 0; kb < S_LEN; kb += 64) {
    __syncthreads();  // protect V_lds (prev iter readers done)
    {   // stage V^T into LDS: [d][key]
      const unsigned short* src = Vbase + (size_t)(kb + vkey) * DHEAD + vdg;
      s16x8 v0 = *(const s16x8*)src;
      s16x8 v1 = *(const s16x8*)(src + 8);
#pragma unroll
      for (int j = 0; j < 8; ++j) V_lds[vdg + j][vkey] = (unsigned short)v0[j];
#pragma unroll
      for (int j = 0; j < 8; ++j) V_lds[vdg + 8 + j][vkey] = (unsigned short)v1[j];
    }
    __syncthreads();

    // ---- QK^T: K fragments straight from global (L2-resident) ----
    f32x4 sc[4];
#pragma unroll
    for (int kg = 0; kg < 4; ++kg) {
      const unsigned short* kp = Kbase + (size_t)(kb + kg * 16 + lr) * DHEAD + lg * 8;
      s16x8 kf0 = *(const s16x8*)kp;
      s16x8 kf1 = *(const s16x8*)(kp + 32);
      f32x4 z = {};
      z = __builtin_amdgcn_mfma_f32_16x16x32_bf16(qf[0], kf0, z, 0, 0, 0);
      sc[kg] = __builtin_amdgcn_mfma_f32_16x16x32_bf16(qf[1], kf1, z, 0, 0, 0);
    }

    // ---- scale + mask (int32 mask: nonzero -> -1e9) ----
#pragma unroll
    for (int kg = 0; kg < 4; ++kg) {
      const int key = kb + kg * 16 + lr;
#pragma unroll
      for (int j = 0; j < 4; ++j) {
        const int qr = qrow0 + lg * 4 + j;
        float sv = sc[kg][j] * 0.03125f;           // 1/sqrt(1024)
        if (mask[(size_t)qr * S_LEN + key]) sv = -1e9f;
        sc[kg][j] = sv;
      }
    }

    // ---- online softmax (rows live in 16-lane groups) ----
    float bmax[4], rs[4];
#pragma unroll
    for (int j = 0; j < 4; ++j)
      bmax[j] = fmaxf(fmaxf(sc[0][j], sc[1][j]), fmaxf(sc[2][j], sc[3][j]));
#pragma unroll
    for (int off = 1; off < 16; off <<= 1)
#pragma unroll
      for (int j = 0; j < 4; ++j)
        bmax[j] = fmaxf(bmax[j], __shfl_xor(bmax[j], off, 64));

    float fac[4];
#pragma unroll
    for (int j = 0; j < 4; ++j) {
      const float mnew = fmaxf(m_run[j], bmax[j]);
      fac[j] = __expf(m_run[j] - mnew);
      m_run[j] = mnew;
      rs[j] = 0.f;
    }
#pragma unroll
    for (int kg = 0; kg < 4; ++kg)
#pragma unroll
      for (int j = 0; j < 4; ++j) {
        const float p = __expf(sc[kg][j] - m_run[j]);
        sc[kg][j] = p;
        rs[j] += p;
      }
#pragma unroll
    for (int off = 1; off < 16; off <<= 1)
#pragma unroll
      for (int j = 0; j < 4; ++j)
        rs[j] += __shfl_xor(rs[j], off, 64);
#pragma unroll
    for (int j = 0; j < 4; ++j)
      l_run[j] = l_run[j] * fac[j] + rs[j];
#pragma unroll
    for (int dg = 0; dg < 4; ++dg)
#pragma unroll
      for (int j = 0; j < 4; ++j)
        o_acc[dg][j] *= fac[j];

    // ---- P (bf16) to per-wave LDS, then PV ----
#pragma unroll
    for (int kg = 0; kg < 4; ++kg)
#pragma unroll
      for (int j = 0; j < 4; ++j)
        P_lds[wid][lg * 4 + j][kg * 16 + lr] = f2bf(sc[kg][j]);
    asm volatile("s_waitcnt lgkmcnt(0)" ::: "memory");
    __builtin_amdgcn_sched_barrier(0);

    s16x8 pf[2];
#pragma unroll
    for (int ks = 0; ks < 2; ++ks)
      pf[ks] = *(const s16x8*)&P_lds[wid][lr][ks * 32 + lg * 8];
#pragma unroll
    for (int dg = 0; dg < 4; ++dg)
#pragma unroll
      for (int ks = 0; ks < 2; ++ks) {
        s16x8 vf = *(const s16x8*)&V_lds[dg * 16 + lr][ks * 32 + lg * 8];
        o_acc[dg] = __builtin_amdgcn_mfma_f32_16x16x32_bf16(pf[ks], vf, o_acc[dg], 0, 0, 0);
      }
  }

  // ---- epilogue: normalize, store bf16 concat [s][h*64+d] ----
#pragma unroll
  for (int dg = 0; dg < 4; ++dg)
#pragma unroll
    for (int j = 0; j < 4; ++j) {
      const int qr = qrow0 + lg * 4 + j;
      const int d = dg * 16 + lr;
      const float val = o_acc[dg][j] / l_run[j];
      concat[(size_t)qr * DMODEL + h * DHEAD + d] = f2bf(val);
    }
}

// ---------------------------------------------------------------------------
extern "C" void kernel_launch(void* const* d_in, const int* in_sizes, int n_in,
                              void* d_out, int out_size, void* d_ws, size_t ws_size,
                              hipStream_t stream) {
  const float* q  = (const float*)d_in[0];
  const float* k  = (const float*)d_in[1];
  const float* v  = (const float*)d_in[2];
  const int* mask = (const int*)d_in[3];  // bool input -> int32 on device
  const float* wq = (const float*)d_in[4];
  const float* bq = (const float*)d_in[5];
  const float* wk = (const float*)d_in[6];
  const float* bk = (const float*)d_in[7];
  const float* wv = (const float*)d_in[8];
  const float* bv = (const float*)d_in[9];
  const float* wo = (const float*)d_in[10];
  const float* bo = (const float*)d_in[11];
  float* out = (float*)d_out;

  // ws layout (bf16): Qh | Kh | Vh (each [16][4096][64]) | concat [4096][1024]
  unsigned short* wsq = (unsigned short*)d_ws;
  unsigned short* wsk = wsq + (size_t)S_LEN * DMODEL;
  unsigned short* wsv = wsk + (size_t)S_LEN * DMODEL;
  unsigned short* wsc = wsv + (size_t)S_LEN * DMODEL;

  dim3 blk(256);
  proj3_kernel<<<dim3(32, 8, 3), blk, 0, stream>>>(q, k, v, wq, bq, wk, bk, wv, bv, wsq);
  attn_fwd<<<dim3(64, 16), blk, 0, stream>>>(wsq, wsk, wsv, mask, wsc);
  outproj_kernel<<<dim3(32, 8), blk, 0, stream>>>(wsc, wo, bo, out);
}